// Round 16
// baseline (19386.943 us; speedup 1.0000x reference)
//
#include <hip/hip_runtime.h>
#include <cmath>

// RNN with Dale's-law recurrent matrix, B=128, S=2000, H=512, I=8, O=2.
// r16 = r15 structural pivot + BIT-EXACT r10 FP ORDER.
// r15 (one 1024-thr block per group, weights streamed from XCD L2, zero
// inter-block sync, ONE barrier/step) ran correctly but failed _tw_ok with
// absmax 0.0234: waves 8..15 accumulated kt 0->15 while the r10 lineage's
// c=1 block accumulated OWN-HALF FIRST (kt 8,10,12,14 then 0,2,4,6 per acc).
// This RNN is chaotic; op-order changes amplify exponentially -- every
// passing kernel is bit-identical (absmax exactly 0.0078125).
// Fix: per-wave kt rotation krot = (w>=8)?8:0; chunk sequence (i+krot)&15
// everywhere in the recurrence (A-tile reads + weight stream, in lockstep).
// Rotation by 8 preserves kt parity -> acc pairing (even->a00, odd->a01)
// unchanged. Out-GEMM stays kt 0..15 (it was c=0's in r10). With identical
// f16 weight bits and identical op order, the trajectory is bit-identical
// to r10 -> absmax 0.0078125.
// Ledger (closed doors, all reverted): per-wave flags r6, stamped publish r7,
// out-blocks r8, post-drain prefetch r9, sc0 flags r1/r11 (hang), K-split
// r4/r5, register-direct C r13, 2-group interleave r14.

constexpr int kS = 2000, kI = 8, kH = 512, kO = 2;
constexpr float kNoiseStd = 0.0005f, kAlpha = 0.1f;

constexpr int GROUPS = 8;    // one block per group of 16 batches
constexpr int NTHR   = 1024; // 16 waves; wave w owns j in [w*32, w*32+32)
constexpr int NBLK   = GROUPS;

typedef _Float16 half8  __attribute__((ext_vector_type(8)));
typedef float    floatx4 __attribute__((ext_vector_type(4)));

#define MFMA16(A, B, C) __builtin_amdgcn_mfma_f32_16x16x32_f16((A), (B), (C), 0, 0, 0)

// tanh(x) = sign(x) * (1 - 2/(exp2(2*log2e*|x|)+1)); overflow saturates to 1.
static __device__ __forceinline__ float fast_tanh(float x) {
  const float ax = __builtin_fabsf(x);
  const float e = __builtin_amdgcn_exp2f(2.8853900817779268f * ax);
  const float r = __builtin_amdgcn_rcpf(e + 1.0f);
  return __builtin_copysignf(__builtin_fmaf(-2.0f, r, 1.0f), x);
}

__global__ __launch_bounds__(NTHR, 4) void rnn_k(
    const float* __restrict__ inp,   // [B,S,I]
    const float* __restrict__ noise, // [B,S,H]
    const float* __restrict__ wi,    // [I,H]
    const float* __restrict__ wexc,  // [384,H]
    const float* __restrict__ winh,  // [128,H]
    const float* __restrict__ wout,  // [H,O]
    const float* __restrict__ h0,    // [H]
    float* __restrict__ out,         // [B,S,O]
    _Float16* __restrict__ wf16)     // ws: [16 kt][16 w][64 lane][16 halves]
{
  const int g = blockIdx.x;     // batch group
  const int tid = threadIdx.x;
  const int w = tid >> 6;       // wave (0..15)
  const int lane = tid & 63;
  const int l15 = lane & 15;
  const int lhi = lane >> 4;

  const int j0 = w * 32 + l15;  // this lane's two output columns
  const int j1 = j0 + 16;
  const int jsub0 = l15 >> 3, jsub1 = 2 + (l15 >> 3), vv = l15 & 7;
  const int krot = (w >= 8) ? 8 : 0;  // own-half-first kt order (r10 FP order)

  __shared__ _Float16 ldsA[2][8192];   // 32KB double-buffered r tile (full H)
  __shared__ half8 ws_wout[16][64];    // 16KB wout fragments
  __shared__ float ldsWI[512][8];      // 16KB wi transposed [j][i]
  __shared__ float ldsIN[2][16][kI];   // inp rows, ping-pong one step ahead

  // ---- convert weights to f16 into ws (all 8 blocks write IDENTICAL bytes;
  // each block then streams its own XCD-L2-resident copy) ----
  _Float16* wbase = wf16 + ((size_t)w * 64 + lane) * 16;  // + kt*16384 halves
  {
    const float* wr0 = (j0 < 384) ? (wexc + (size_t)j0 * kH) : (winh + (size_t)(j0 - 384) * kH);
    const float* wr1 = (j1 < 384) ? (wexc + (size_t)j1 * kH) : (winh + (size_t)(j1 - 384) * kH);
#pragma unroll
    for (int kt = 0; kt < 16; ++kt) {
      half8 b0, b1;
#pragma unroll
      for (int v = 0; v < 8; ++v) {
        b0[v] = (_Float16)wr0[kt * 32 + lhi * 8 + v];
        b1[v] = (_Float16)wr1[kt * 32 + lhi * 8 + v];
      }
      *(half8*)(wbase + (size_t)kt * 16384)     = b0;
      *(half8*)(wbase + (size_t)kt * 16384 + 8) = b1;
    }
  }

  if (w < 4) {
#pragma unroll
    for (int t = 0; t < 4; ++t) {
      const int kt = w * 4 + t;
      const int k0 = kt * 32 + lhi * 8;
      half8 hv;
#pragma unroll
      for (int v = 0; v < 8; ++v)
        hv[v] = (l15 < kO) ? (_Float16)wout[(size_t)(k0 + v) * kO + l15] : (_Float16)0.f;
      ws_wout[kt][lane] = hv;
    }
  }
  if (tid < 512) {
#pragma unroll
    for (int i = 0; i < 8; ++i) ldsWI[tid][i] = wi[i * kH + tid];
  }
  if (w == 2 || w == 3) {
    const int ii = tid - 128;
    ldsIN[0][ii >> 3][ii & 7] = inp[((size_t)(g * 16 + (ii >> 3)) * kS + 0) * kI + (ii & 7)];
  }

  // ---- init h, write r_0 (own chunk; chunk index = w) into ldsA[0] ----
  float hq0[4], hq1[4];
  {
    const float h00 = h0[j0], h01 = h0[j1];
#pragma unroll
    for (int q = 0; q < 4; ++q) { hq0[q] = h00; hq1[q] = h01; }
    const _Float16 r00 = (_Float16)fast_tanh(h00);
    const _Float16 r01 = (_Float16)fast_tanh(h01);
#pragma unroll
    for (int q = 0; q < 4; ++q) {
      const int bb = lhi * 4 + q;
      ldsA[0][w * 512 + (bb + 16 * jsub0) * 8 + vv] = r00;
      ldsA[0][w * 512 + (bb + 16 * jsub1) * 8 + vv] = r01;
    }
  }
  __syncthreads();  // wf16 stores drained (vmcnt 0); LDS init visible

  // ---- preload weight chunks seq[0..3] = (krot..krot+3)&15 ----
  half8 wA0[4], wA1[4], wB0[4], wB1[4];
#pragma unroll
  for (int t = 0; t < 4; ++t) {
    const _Float16* p = wbase + (size_t)((t + krot) & 15) * 16384;
    wA0[t] = *(const half8*)p; wA1[t] = *(const half8*)(p + 8);
  }

  // chunk index for pipeline position X is (X + krot) & 15, applied to BOTH
  // the weight stream and the A-tile read (lockstep -> correct k-pairing).
#define LDCHUNK(B0, B1, KTBASE)                                              \
  _Pragma("unroll")                                                          \
  for (int t = 0; t < 4; ++t) {                                              \
    const _Float16* p = wbase + (size_t)(((KTBASE) + t + krot) & 15) * 16384; \
    B0[t] = *(const half8*)p; B1[t] = *(const half8*)(p + 8);                \
  }
#define CK(KT, B0, B1)                                                       \
  {                                                                          \
    const int kk = ((KT) + krot) & 15;                                       \
    const half8 f = *(const half8*)(base + kk * 1024 + lane * 16);           \
    if ((KT) & 1) { a01 = MFMA16(f, B0, a01); a11 = MFMA16(f, B1, a11); }    \
    else          { a00 = MFMA16(f, B0, a00); a10 = MFMA16(f, B1, a10); }    \
  }

  // ---- main loop: one barrier per step, zero global synchronization ----
  for (int s = 0; s < kS; ++s) {
    const int cur = s & 1;
    const bool lastS = (s == kS - 1);
    const char* base = (const char*)&ldsA[cur][0];

    // out row s (wave 15) from ldsA[cur] -- stable all step (D writes cur^1).
    // kt order 0..15 (r10's c=0 out-GEMM order).
    if (w == 15) {
      floatx4 oa = {0,0,0,0}, ob = {0,0,0,0};
#pragma unroll
      for (int kt = 0; kt < 16; kt += 2) {
        const half8 f0 = *(const half8*)(base + kt * 1024 + lane * 16);
        const half8 f1 = *(const half8*)(base + (kt + 1) * 1024 + lane * 16);
        oa = MFMA16(f0, ws_wout[kt][lane], oa);
        ob = MFMA16(f1, ws_wout[kt + 1][lane], ob);
      }
      if (l15 < kO) {
#pragma unroll
        for (int q = 0; q < 4; ++q)
          out[((size_t)(g * 16 + lhi * 4 + q) * kS + s) * kO + l15] = oa[q] + ob[q];
      }
    }
    if (lastS) break;  // nothing else needed at s=1999

    // noise row s + inp row s+1 (compiler-managed; ride under the MFMA phase)
    float nz0[4], nz1[4];
#pragma unroll
    for (int q = 0; q < 4; ++q) {
      const int b = g * 16 + lhi * 4 + q;
      nz0[q] = noise[((size_t)b * kS + s) * kH + j0];
      nz1[q] = noise[((size_t)b * kS + s) * kH + j1];
    }
    float invN = 0.f;
    if (s < kS - 2 && (w == 2 || w == 3)) {
      const int ii = tid - 128;
      invN = inp[((size_t)(g * 16 + (ii >> 3)) * kS + (s + 1)) * kI + (ii & 7)];
    }

    // MFMA phase: 16 kt in rotated order, 4-kt chunks, double-buffered weight
    // stream from L2. ch3 prefetches seq[0..3] for the NEXT step (weights are
    // step-invariant); the barrier's vmcnt drain overlaps D-phase VALU.
    floatx4 a00 = {0,0,0,0}, a01 = {0,0,0,0}, a10 = {0,0,0,0}, a11 = {0,0,0,0};
    LDCHUNK(wB0, wB1, 4)                                  // ch1 prefetch
    CK(0, wA0[0], wA1[0]) CK(1, wA0[1], wA1[1])
    CK(2, wA0[2], wA1[2]) CK(3, wA0[3], wA1[3])
    LDCHUNK(wA0, wA1, 8)                                  // ch2 prefetch
    CK(4, wB0[0], wB1[0]) CK(5, wB0[1], wB1[1])
    CK(6, wB0[2], wB1[2]) CK(7, wB0[3], wB1[3])
    LDCHUNK(wB0, wB1, 12)                                 // ch3 prefetch
    CK(8, wA0[0], wA1[0]) CK(9, wA0[1], wA1[1])
    CK(10, wA0[2], wA1[2]) CK(11, wA0[3], wA1[3])
    LDCHUNK(wA0, wA1, 0)                                  // next step's ch0
    CK(12, wB0[0], wB1[0]) CK(13, wB0[1], wB1[1])
    CK(14, wB0[2], wB1[2]) CK(15, wB0[3], wB1[3])

    // D-phase: h update, write r_{s+1} into ldsA[cur^1]; stage inp row s+1
    if (s < kS - 2 && (w == 2 || w == 3)) {
      const int ii = tid - 128;
      ldsIN[(s + 1) & 1][ii >> 3][ii & 7] = invN;
    }
    {
      _Float16* lA = &ldsA[cur ^ 1][0];
      const floatx4 wv0a = *(const floatx4*)&ldsWI[j0][0];
      const floatx4 wv0b = *(const floatx4*)&ldsWI[j0][4];
      const floatx4 wv1a = *(const floatx4*)&ldsWI[j1][0];
      const floatx4 wv1b = *(const floatx4*)&ldsWI[j1][4];
#pragma unroll
      for (int q = 0; q < 4; ++q) {
        const int bb = lhi * 4 + q;
        const floatx4 iv0 = *(const floatx4*)&ldsIN[cur][bb][0];
        const floatx4 iv1 = *(const floatx4*)&ldsIN[cur][bb][4];
        float x0 = 0.f, x1 = 0.f;
#pragma unroll
        for (int i = 0; i < 4; ++i) {
          x0 = fmaf(iv0[i], wv0a[i], x0); x0 = fmaf(iv1[i], wv0b[i], x0);
          x1 = fmaf(iv0[i], wv1a[i], x1); x1 = fmaf(iv1[i], wv1b[i], x1);
        }
        const float y0 = a00[q] + a01[q], y1 = a10[q] + a11[q];
        const float h0n = hq0[q] + kNoiseStd * nz0[q] + kAlpha * (-hq0[q] + y0 + x0);
        const float h1n = hq1[q] + kNoiseStd * nz1[q] + kAlpha * (-hq1[q] + y1 + x1);
        hq0[q] = h0n; hq1[q] = h1n;
        lA[w * 512 + (bb + 16 * jsub0) * 8 + vv] = (_Float16)fast_tanh(h0n);
        lA[w * 512 + (bb + 16 * jsub1) * 8 + vv] = (_Float16)fast_tanh(h1n);
      }
    }
    __syncthreads();  // the ONE barrier: r_{s+1} tile complete; drains loads
  }
}

extern "C" void kernel_launch(void* const* d_in, const int* in_sizes, int n_in,
                              void* d_out, int out_size, void* d_ws, size_t ws_size,
                              hipStream_t stream) {
  const float* inp   = (const float*)d_in[0];
  const float* noise = (const float*)d_in[1];
  const float* wi    = (const float*)d_in[2];
  const float* wexc  = (const float*)d_in[3];
  const float* winh  = (const float*)d_in[4];
  const float* wout  = (const float*)d_in[5];
  const float* h0    = (const float*)d_in[6];

  // ws: 512KB f16 weight image, fully rewritten by every block each launch.
  // No flags, no memset, no protocol state.
  rnn_k<<<NBLK, NTHR, 0, stream>>>(inp, noise, wi, wexc, winh, wout, h0,
                                   (float*)d_out, (_Float16*)d_ws);
}